// Round 5
// baseline (650.104 us; speedup 1.0000x reference)
//
#include <hip/hip_runtime.h>
#include <hip/hip_bf16.h>

#define DD 768
#define HH 3072
#define NE 8
#define TOPK 2

#define BK 64
#define NB1 (HH / 128)   // 24 col blocks, gemm1
#define NB2 (DD / 128)   // 6 col blocks, gemm2

typedef __attribute__((ext_vector_type(8))) short short8;
typedef __attribute__((ext_vector_type(4))) float f32x4;

static __device__ __forceinline__ unsigned short f2bf(float v) {
    __hip_bfloat16 b = __float2bfloat16(v);
    return *reinterpret_cast<unsigned short*>(&b);
}

// ---------------- weight conversion fp32 -> bf16 ----------------
__global__ __launch_bounds__(256) void convert_kernel(
    const float* __restrict__ w1, const float* __restrict__ w2,
    unsigned short* __restrict__ w1b, unsigned short* __restrict__ w2b, size_t n)
{
    size_t tid = (size_t)blockIdx.x * blockDim.x + threadIdx.x;
    size_t stride = (size_t)gridDim.x * blockDim.x;
    size_t quarter = n / 4;            // float4 count per tensor
    size_t tot = 2 * quarter;
    for (size_t j = tid; j < tot; j += stride) {
        const float* src; unsigned short* dst; size_t off;
        if (j < quarter) { src = w1; dst = w1b; off = j * 4; }
        else             { src = w2; dst = w2b; off = (j - quarter) * 4; }
        float4 v = *reinterpret_cast<const float4*>(&src[off]);
        ushort4 o;
        o.x = f2bf(v.x); o.y = f2bf(v.y); o.z = f2bf(v.z); o.w = f2bf(v.w);
        *reinterpret_cast<ushort4*>(&dst[off]) = o;
    }
}

// ---------------- init control block + token_map ----------------
// ctrl: [0..8) counts | [8..16) scatter cursors | [16..25) row offsets |
//       [26] g1 item cursor | [27] g2 item cursor |
//       [32..41) g1 item prefix | [41..50) g2 item prefix
__global__ __launch_bounds__(256) void init_kernel(int* token_map, int* ctrl, int maxP)
{
    int i = blockIdx.x * blockDim.x + threadIdx.x;
    if (i < maxP) token_map[i] = -1;
    if (i < 64) ctrl[i] = 0;
}

// ---------------- gate: logits, top-2, softmax ----------------
__global__ __launch_bounds__(256) void gate_kernel(
    const float* __restrict__ x, const float* __restrict__ gw, const float* __restrict__ gb,
    int* __restrict__ topk_idx, float* __restrict__ topk_w, int* __restrict__ ctrl, int T)
{
    int t = blockIdx.x * 4 + (threadIdx.x >> 6);
    int lane = threadIdx.x & 63;
    if (t >= T) return;
    float acc[NE];
#pragma unroll
    for (int e = 0; e < NE; ++e) acc[e] = 0.f;
    const float* xr = x + (size_t)t * DD;
    for (int d = lane; d < DD; d += 64) {
        float xv = xr[d];
#pragma unroll
        for (int e = 0; e < NE; ++e) acc[e] += xv * gw[e * DD + d];
    }
#pragma unroll
    for (int e = 0; e < NE; ++e) {
        float v = acc[e];
        for (int off = 32; off; off >>= 1) v += __shfl_xor(v, off, 64);
        acc[e] = v;
    }
    if (lane == 0) {
        float lg[NE];
#pragma unroll
        for (int e = 0; e < NE; ++e) lg[e] = acc[e] + gb[e];
        int i0 = 0;
#pragma unroll
        for (int e = 1; e < NE; ++e) if (lg[e] > lg[i0]) i0 = e;
        int i1 = -1;
#pragma unroll
        for (int e = 0; e < NE; ++e) {
            if (e == i0) continue;
            if (i1 < 0 || lg[e] > lg[i1]) i1 = e;
        }
        float m = lg[i0];
        float e0 = __expf(lg[i0] - m), e1 = __expf(lg[i1] - m);
        float s = e0 + e1;
        topk_idx[2 * t]     = i0;
        topk_idx[2 * t + 1] = i1;
        topk_w[2 * t]       = e0 / s;
        topk_w[2 * t + 1]   = e1 / s;
        atomicAdd(&ctrl[i0], 1);
        atomicAdd(&ctrl[i1], 1);
    }
}

// ---------------- offsets + work-item enumeration ----------------
__global__ void offsets_kernel(int* ctrl)
{
    if (threadIdx.x == 0 && blockIdx.x == 0) {
        int acc = 0, it1 = 0, it2 = 0;
        for (int e = 0; e < NE; ++e) {
            ctrl[16 + e] = acc;
            int nrb = (ctrl[e] + 127) >> 7;        // active 128-row blocks
            acc += nrb << 7;
            ctrl[32 + e] = it1; it1 += nrb * NB1;
            ctrl[41 + e] = it2; it2 += nrb * NB2;
        }
        ctrl[24] = acc;      // total padded rows
        ctrl[40] = it1;      // total gemm1 items
        ctrl[49] = it2;      // total gemm2 items
    }
}

// ---------------- scatter assignments to expert segments ----------------
__global__ __launch_bounds__(256) void scatter_kernel(
    const int* __restrict__ topk_idx, const float* __restrict__ topk_w,
    int* ctrl, int* token_map, int* pos_of, float* wpos, int nA)
{
    int a = blockIdx.x * blockDim.x + threadIdx.x;
    if (a >= nA) return;
    int e = topk_idx[a];
    int p = ctrl[16 + e] + atomicAdd(&ctrl[8 + e], 1);
    token_map[p] = a;
    pos_of[a] = p;
    wpos[p] = topk_w[a];
}

// ---------------- gather x rows -> bf16 Xe ----------------
__global__ __launch_bounds__(256) void gather_kernel(
    const float* __restrict__ x, const int* __restrict__ token_map,
    unsigned short* __restrict__ Xe, int maxP)
{
    int i = blockIdx.x * blockDim.x + threadIdx.x;
    int total = maxP * (DD / 4);
    if (i >= total) return;
    int r = i / (DD / 4);
    int c = (i % (DD / 4)) * 4;
    int a = token_map[r];
    ushort4 o;
    if (a < 0) {
        o.x = o.y = o.z = o.w = 0;
    } else {
        float4 v = *reinterpret_cast<const float4*>(&x[(size_t)(a >> 1) * DD + c]);
        o.x = f2bf(v.x); o.y = f2bf(v.y); o.z = f2bf(v.z); o.w = f2bf(v.w);
    }
    *reinterpret_cast<ushort4*>(&Xe[(size_t)r * DD + c]) = o;
}

// ---------------- staging: 128 rows x 64 cols bf16 tile -> LDS ----------------
// Linear LDS dest + inverse-XOR-swizzled per-lane global source (verified: 0 conflicts).
// Chunk (row,kc) lives at LDS chunk row*8 + (kc ^ (row&7)); reader applies same XOR.
static __device__ __forceinline__ void stage_tile(
    const unsigned short* __restrict__ g, int ld, unsigned short* __restrict__ lds)
{
    int tid = threadIdx.x;   // 256 threads, 4 chunks each
#pragma unroll
    for (int r = 0; r < 4; ++r) {
        int j = (r << 8) + tid;           // chunk idx 0..1023
        int row = j >> 3;
        int kc = (j & 7) ^ (row & 7);     // inverse swizzle on SOURCE
        __builtin_amdgcn_global_load_lds(
            (const __attribute__((address_space(1))) void*)(g + (size_t)row * ld + (kc << 3)),
            (__attribute__((address_space(3))) void*)(lds + (j << 3)),
            16, 0, 0);
    }
}

#define LDSF(base, row, kc) \
    reinterpret_cast<const short8*>(&(base)[((((row) << 3) + ((kc) ^ ((row) & 7))) << 3)])

// ---------------- single-buffered K-loop, TLP-covered (m97 regime) ----------------
// Per K-tile: stage A,B -> __syncthreads (vmcnt drain) -> ds_read + 32 MFMA ->
// __syncthreads. 32 KB LDS -> 4 blocks/CU; co-resident blocks at uncorrelated
// phases cover each other's stage latency (the m114/m97 mechanism).
static __device__ __forceinline__ void gemm_item(
    const unsigned short* __restrict__ Abase,
    const unsigned short* __restrict__ Bbase,
    int ld, int nt,
    unsigned short* __restrict__ As, unsigned short* __restrict__ Bs, // each [8192]
    f32x4 acc[4][4], int wr, int wc, int fr, int fq)
{
    for (int t = 0; t < nt; ++t) {
        stage_tile(Abase + (size_t)t * BK, ld, As);
        stage_tile(Bbase + (size_t)t * BK, ld, Bs);
        __syncthreads();                       // drains vmcnt: tile visible
        short8 a[2][4], b[2][4];
#pragma unroll
        for (int ks = 0; ks < 2; ++ks) {
            int kc = ks * 4 + fq;
#pragma unroll
            for (int m = 0; m < 4; ++m)
                a[ks][m] = *LDSF(As, wr + m * 16 + fr, kc);
#pragma unroll
            for (int n = 0; n < 4; ++n)
                b[ks][n] = *LDSF(Bs, wc + n * 16 + fr, kc);
        }
        __builtin_amdgcn_s_setprio(1);
#pragma unroll
        for (int ks = 0; ks < 2; ++ks)
#pragma unroll
            for (int m = 0; m < 4; ++m)
#pragma unroll
                for (int n = 0; n < 4; ++n)
                    acc[m][n] = __builtin_amdgcn_mfma_f32_16x16x32_bf16(
                        a[ks][m], b[ks][n], acc[m][n], 0, 0, 0);
        __builtin_amdgcn_s_setprio(0);
        __syncthreads();                       // readers done before next stage
    }
}

// ---------------- GEMM1: persistent work-queue, H1 = gelu(Xe@w1^T+b1) ----------------
__global__ __launch_bounds__(256, 4) void gemm1_kernel(
    const unsigned short* __restrict__ Xe, const unsigned short* __restrict__ W1b,
    const float* __restrict__ b1, unsigned short* __restrict__ H1,
    int* __restrict__ ctrl)
{
    __shared__ unsigned short As[128 * 64];
    __shared__ unsigned short Bs[128 * 64];
    __shared__ int sh_item;

    int tid = threadIdx.x, lane = tid & 63, w = tid >> 6;
    int wr = (w >> 1) * 64, wc = (w & 1) * 64;
    int fr = lane & 15, fq = lane >> 4;
    int tot = ctrl[40];

    for (;;) {
        if (tid == 0) sh_item = atomicAdd(&ctrl[26], 1);
        __syncthreads();
        int item = sh_item;
        if (item >= tot) return;

        // decode item -> (expert e, col block cb, row block rb); rb fast so
        // consecutive poppers share the same B panel (L2/L3 broadcast).
        int e = 7;
        while (item < ctrl[32 + e]) --e;
        int loc = item - ctrl[32 + e];
        int segbase = ctrl[16 + e];
        int nrb = (ctrl[17 + e] - segbase) >> 7;
        int cb = loc / nrb;
        int rb = loc - cb * nrb;
        int rowbase = segbase + (rb << 7);
        int colbase = cb << 7;

        const unsigned short* Abase = Xe + (size_t)rowbase * DD;
        const unsigned short* Bbase = W1b + (size_t)e * HH * DD + (size_t)colbase * DD;

        f32x4 acc[4][4];
#pragma unroll
        for (int m = 0; m < 4; ++m)
#pragma unroll
            for (int n = 0; n < 4; ++n) acc[m][n] = (f32x4){0.f, 0.f, 0.f, 0.f};

        gemm_item(Abase, Bbase, DD, DD / BK, As, Bs, acc, wr, wc, fr, fq);

#pragma unroll
        for (int m = 0; m < 4; ++m) {
            int row0 = rowbase + wr + m * 16 + fq * 4;
#pragma unroll
            for (int n = 0; n < 4; ++n) {
                int col = colbase + wc + n * 16 + fr;
                float bb = b1[e * HH + col];
#pragma unroll
                for (int r = 0; r < 4; ++r) {
                    float v = acc[m][n][r] + bb;
                    v = 0.5f * v * (1.f + erff(v * 0.70710678118f));
                    H1[(size_t)(row0 + r) * HH + col] = f2bf(v);
                }
            }
        }
    }
}

// ---------------- GEMM2: persistent work-queue, Yb = wpos*(H1@w2^T+b2) ----------------
__global__ __launch_bounds__(256, 4) void gemm2_kernel(
    const unsigned short* __restrict__ H1, const unsigned short* __restrict__ W2b,
    const float* __restrict__ b2, const float* __restrict__ wpos,
    float* __restrict__ Yb, int* __restrict__ ctrl)
{
    __shared__ unsigned short As[128 * 64];
    __shared__ unsigned short Bs[128 * 64];
    __shared__ int sh_item;

    int tid = threadIdx.x, lane = tid & 63, w = tid >> 6;
    int wr = (w >> 1) * 64, wc = (w & 1) * 64;
    int fr = lane & 15, fq = lane >> 4;
    int tot = ctrl[49];

    for (;;) {
        if (tid == 0) sh_item = atomicAdd(&ctrl[27], 1);
        __syncthreads();
        int item = sh_item;
        if (item >= tot) return;

        int e = 7;
        while (item < ctrl[41 + e]) --e;
        int loc = item - ctrl[41 + e];
        int segbase = ctrl[16 + e];
        int nrb = (ctrl[17 + e] - segbase) >> 7;
        int cb = loc / nrb;
        int rb = loc - cb * nrb;
        int rowbase = segbase + (rb << 7);
        int colbase = cb << 7;

        const unsigned short* Abase = H1 + (size_t)rowbase * HH;
        const unsigned short* Bbase = W2b + (size_t)e * DD * HH + (size_t)colbase * HH;

        f32x4 acc[4][4];
#pragma unroll
        for (int m = 0; m < 4; ++m)
#pragma unroll
            for (int n = 0; n < 4; ++n) acc[m][n] = (f32x4){0.f, 0.f, 0.f, 0.f};

        gemm_item(Abase, Bbase, HH, HH / BK, As, Bs, acc, wr, wc, fr, fq);

#pragma unroll
        for (int m = 0; m < 4; ++m) {
            int row0 = rowbase + wr + m * 16 + fq * 4;
            float wp[4];
#pragma unroll
            for (int r = 0; r < 4; ++r) wp[r] = wpos[row0 + r];
#pragma unroll
            for (int n = 0; n < 4; ++n) {
                int col = colbase + wc + n * 16 + fr;
                float bb = b2[e * DD + col];
#pragma unroll
                for (int r = 0; r < 4; ++r) {
                    float v = acc[m][n][r] + bb;
                    Yb[(size_t)(row0 + r) * DD + col] = wp[r] * v;
                }
            }
        }
    }
}

// ---------------- combine: out[t] = Yb[pos0] + Yb[pos1]; bias passthrough ----------------
__global__ __launch_bounds__(256) void combine_kernel(
    const float* __restrict__ Yb, const int* __restrict__ pos_of,
    const float* __restrict__ bias, float* __restrict__ out, int T)
{
    int i = blockIdx.x * blockDim.x + threadIdx.x;
    int total = T * (DD / 4);
    if (i < total) {
        int t = i / (DD / 4);
        int c = (i % (DD / 4)) * 4;
        int p0 = pos_of[2 * t], p1 = pos_of[2 * t + 1];
        float4 v0 = *reinterpret_cast<const float4*>(&Yb[(size_t)p0 * DD + c]);
        float4 v1 = *reinterpret_cast<const float4*>(&Yb[(size_t)p1 * DD + c]);
        float4 o;
        o.x = v0.x + v1.x; o.y = v0.y + v1.y; o.z = v0.z + v1.z; o.w = v0.w + v1.w;
        *reinterpret_cast<float4*>(&out[(size_t)t * DD + c]) = o;
    } else if (i < total + DD / 4) {
        int c = (i - total) * 4;
        *reinterpret_cast<float4*>(&out[(size_t)T * DD + c]) =
            *reinterpret_cast<const float4*>(&bias[c]);
    }
}

extern "C" void kernel_launch(void* const* d_in, const int* in_sizes, int n_in,
                              void* d_out, int out_size, void* d_ws, size_t ws_size,
                              hipStream_t stream)
{
    const float* x    = (const float*)d_in[0];
    const float* gw   = (const float*)d_in[1];
    const float* gb   = (const float*)d_in[2];
    const float* w1   = (const float*)d_in[3];
    const float* b1   = (const float*)d_in[4];
    const float* w2   = (const float*)d_in[5];
    const float* b2   = (const float*)d_in[6];
    const float* bias = (const float*)d_in[7];
    float* out = (float*)d_out;

    int T = in_sizes[0] / DD;
    int nA = T * TOPK;
    int maxP = nA + NE * 128;

    char* ws = (char*)d_ws;
    size_t off = 0;
    auto alloc = [&](size_t bytes) -> char* {
        char* p = ws + off;
        off += (bytes + 255) & ~(size_t)255;
        return p;
    };
    unsigned short* w1b = (unsigned short*)alloc((size_t)NE * HH * DD * 2);
    unsigned short* w2b = (unsigned short*)alloc((size_t)NE * DD * HH * 2);
    unsigned short* Xe  = (unsigned short*)alloc((size_t)maxP * DD * 2);
    unsigned short* H1  = (unsigned short*)alloc((size_t)maxP * HH * 2);
    float*  Yb          = (float*)alloc((size_t)maxP * DD * 4);
    int*    topk_idx    = (int*)alloc((size_t)nA * 4);
    float*  topk_w      = (float*)alloc((size_t)nA * 4);
    int*    pos_of      = (int*)alloc((size_t)nA * 4);
    float*  wpos        = (float*)alloc((size_t)maxP * 4);
    int*    token_map   = (int*)alloc((size_t)maxP * 4);
    int*    ctrl        = (int*)alloc(64 * 4);

    size_t nW = (size_t)NE * HH * DD;

    hipLaunchKernelGGL(convert_kernel, dim3(4096), dim3(256), 0, stream,
                       w1, w2, w1b, w2b, nW);
    hipLaunchKernelGGL(init_kernel, dim3((maxP + 255) / 256), dim3(256), 0, stream,
                       token_map, ctrl, maxP);
    hipLaunchKernelGGL(gate_kernel, dim3((T + 3) / 4), dim3(256), 0, stream,
                       x, gw, gb, topk_idx, topk_w, ctrl, T);
    hipLaunchKernelGGL(offsets_kernel, dim3(1), dim3(64), 0, stream, ctrl);
    hipLaunchKernelGGL(scatter_kernel, dim3((nA + 255) / 256), dim3(256), 0, stream,
                       topk_idx, topk_w, ctrl, token_map, pos_of, wpos, nA);
    hipLaunchKernelGGL(gather_kernel, dim3((maxP * (DD / 4) + 255) / 256), dim3(256), 0, stream,
                       x, token_map, Xe, maxP);
    hipLaunchKernelGGL(gemm1_kernel, dim3(1024), dim3(256), 0, stream,
                       Xe, w1b, b1, H1, ctrl);
    hipLaunchKernelGGL(gemm2_kernel, dim3(1024), dim3(256), 0, stream,
                       H1, w2b, b2, wpos, Yb, ctrl);
    hipLaunchKernelGGL(combine_kernel, dim3((T * (DD / 4) + DD / 4 + 255) / 256, 1, 1), dim3(256), 0, stream,
                       Yb, pos_of, bias, out, T);
}

// Round 6
// 398.536 us; speedup vs baseline: 1.6312x; 1.6312x over previous
//
#include <hip/hip_runtime.h>
#include <hip/hip_bf16.h>

#define DD 768
#define HH 3072
#define NE 8
#define TOPK 2

#define BK 64
#define NB1 (HH / 128)   // 24 col blocks, gemm1
#define NB2 (DD / 128)   // 6 col blocks, gemm2
#define SK2 2            // gemm2 K-split factor

typedef __attribute__((ext_vector_type(8))) short short8;
typedef __attribute__((ext_vector_type(4))) float f32x4;

static __device__ __forceinline__ unsigned short f2bf(float v) {
    __hip_bfloat16 b = __float2bfloat16(v);
    return *reinterpret_cast<unsigned short*>(&b);
}

// ---------------- weight conversion fp32 -> bf16 ----------------
__global__ __launch_bounds__(256) void convert_kernel(
    const float* __restrict__ w1, const float* __restrict__ w2,
    unsigned short* __restrict__ w1b, unsigned short* __restrict__ w2b, size_t n)
{
    size_t tid = (size_t)blockIdx.x * blockDim.x + threadIdx.x;
    size_t stride = (size_t)gridDim.x * blockDim.x;
    size_t quarter = n / 4;            // float4 count per tensor
    size_t tot = 2 * quarter;
    for (size_t j = tid; j < tot; j += stride) {
        const float* src; unsigned short* dst; size_t off;
        if (j < quarter) { src = w1; dst = w1b; off = j * 4; }
        else             { src = w2; dst = w2b; off = (j - quarter) * 4; }
        float4 v = *reinterpret_cast<const float4*>(&src[off]);
        ushort4 o;
        o.x = f2bf(v.x); o.y = f2bf(v.y); o.z = f2bf(v.z); o.w = f2bf(v.w);
        *reinterpret_cast<ushort4*>(&dst[off]) = o;
    }
}

// ---------------- init control block + token_map ----------------
// ctrl: [0..8) counts | [8..16) scatter cursors | [16..25) row offsets |
//       [26] g1 item cursor | [27] g2 item cursor |
//       [32..41) g1 item prefix | [41..50) g2 item prefix
__global__ __launch_bounds__(256) void init_kernel(int* token_map, int* ctrl, int maxP)
{
    int i = blockIdx.x * blockDim.x + threadIdx.x;
    if (i < maxP) token_map[i] = -1;
    if (i < 64) ctrl[i] = 0;
}

// ---------------- gate: logits, top-2, softmax ----------------
__global__ __launch_bounds__(256) void gate_kernel(
    const float* __restrict__ x, const float* __restrict__ gw, const float* __restrict__ gb,
    int* __restrict__ topk_idx, float* __restrict__ topk_w, int* __restrict__ ctrl, int T)
{
    int t = blockIdx.x * 4 + (threadIdx.x >> 6);
    int lane = threadIdx.x & 63;
    if (t >= T) return;
    float acc[NE];
#pragma unroll
    for (int e = 0; e < NE; ++e) acc[e] = 0.f;
    const float* xr = x + (size_t)t * DD;
    for (int d = lane; d < DD; d += 64) {
        float xv = xr[d];
#pragma unroll
        for (int e = 0; e < NE; ++e) acc[e] += xv * gw[e * DD + d];
    }
#pragma unroll
    for (int e = 0; e < NE; ++e) {
        float v = acc[e];
        for (int off = 32; off; off >>= 1) v += __shfl_xor(v, off, 64);
        acc[e] = v;
    }
    if (lane == 0) {
        float lg[NE];
#pragma unroll
        for (int e = 0; e < NE; ++e) lg[e] = acc[e] + gb[e];
        int i0 = 0;
#pragma unroll
        for (int e = 1; e < NE; ++e) if (lg[e] > lg[i0]) i0 = e;
        int i1 = -1;
#pragma unroll
        for (int e = 0; e < NE; ++e) {
            if (e == i0) continue;
            if (i1 < 0 || lg[e] > lg[i1]) i1 = e;
        }
        float m = lg[i0];
        float e0 = __expf(lg[i0] - m), e1 = __expf(lg[i1] - m);
        float s = e0 + e1;
        topk_idx[2 * t]     = i0;
        topk_idx[2 * t + 1] = i1;
        topk_w[2 * t]       = e0 / s;
        topk_w[2 * t + 1]   = e1 / s;
        atomicAdd(&ctrl[i0], 1);
        atomicAdd(&ctrl[i1], 1);
    }
}

// ---------------- offsets + work-item enumeration ----------------
__global__ void offsets_kernel(int* ctrl)
{
    if (threadIdx.x == 0 && blockIdx.x == 0) {
        int acc = 0, it1 = 0, it2 = 0;
        for (int e = 0; e < NE; ++e) {
            ctrl[16 + e] = acc;
            int nrb = (ctrl[e] + 127) >> 7;        // active 128-row blocks
            acc += nrb << 7;
            ctrl[32 + e] = it1; it1 += nrb * NB1;
            ctrl[41 + e] = it2; it2 += nrb * NB2 * SK2;
        }
        ctrl[24] = acc;      // total padded rows
        ctrl[40] = it1;      // total gemm1 items
        ctrl[49] = it2;      // total gemm2 items
    }
}

// ---------------- scatter assignments to expert segments ----------------
__global__ __launch_bounds__(256) void scatter_kernel(
    const int* __restrict__ topk_idx, const float* __restrict__ topk_w,
    int* ctrl, int* token_map, int* pos_of, float* wpos, int nA)
{
    int a = blockIdx.x * blockDim.x + threadIdx.x;
    if (a >= nA) return;
    int e = topk_idx[a];
    int p = ctrl[16 + e] + atomicAdd(&ctrl[8 + e], 1);
    token_map[p] = a;
    pos_of[a] = p;
    wpos[p] = topk_w[a];
}

// ---------------- gather x rows -> bf16 Xe ----------------
__global__ __launch_bounds__(256) void gather_kernel(
    const float* __restrict__ x, const int* __restrict__ token_map,
    unsigned short* __restrict__ Xe, int maxP)
{
    int i = blockIdx.x * blockDim.x + threadIdx.x;
    int total = maxP * (DD / 4);
    if (i >= total) return;
    int r = i / (DD / 4);
    int c = (i % (DD / 4)) * 4;
    int a = token_map[r];
    ushort4 o;
    if (a < 0) {
        o.x = o.y = o.z = o.w = 0;
    } else {
        float4 v = *reinterpret_cast<const float4*>(&x[(size_t)(a >> 1) * DD + c]);
        o.x = f2bf(v.x); o.y = f2bf(v.y); o.z = f2bf(v.z); o.w = f2bf(v.w);
    }
    *reinterpret_cast<ushort4*>(&Xe[(size_t)r * DD + c]) = o;
}

// ---------------- staging: 128 rows x 64 cols bf16 tile -> LDS ----------------
// Linear LDS dest + inverse-XOR-swizzled per-lane global source (verified: 0 conflicts).
// Chunk (row,kc) lives at LDS chunk row*8 + (kc ^ (row&7)); reader applies same XOR.
static __device__ __forceinline__ void stage_tile(
    const unsigned short* __restrict__ g, int ld, unsigned short* __restrict__ lds)
{
    int tid = threadIdx.x;   // 256 threads, 4 chunks each
#pragma unroll
    for (int r = 0; r < 4; ++r) {
        int j = (r << 8) + tid;           // chunk idx 0..1023
        int row = j >> 3;
        int kc = (j & 7) ^ (row & 7);     // inverse swizzle on SOURCE
        __builtin_amdgcn_global_load_lds(
            (const __attribute__((address_space(1))) void*)(g + (size_t)row * ld + (kc << 3)),
            (__attribute__((address_space(3))) void*)(lds + (j << 3)),
            16, 0, 0);
    }
}

#define LDSF(base, row, kc) \
    reinterpret_cast<const short8*>(&(base)[((((row) << 3) + ((kc) ^ ((row) & 7))) << 3)])

// ---------------- dbuf K-loop with counted vmcnt (never drained in-loop) ----------------
// Iter t: issue stage(t+1 -> buf^1); s_waitcnt vmcnt(8) => tile t landed, tile t+1's
// 8 loads stay in flight across the barrier; raw s_barrier; ds_read+32 MFMA;
// lgkmcnt(0); raw s_barrier (readers done -> buf^1's old contents reusable next iter).
// The t+1 loads get a full iteration (~1000 cy) of cover. Round-2-verified pattern.
static __device__ __forceinline__ void gemm_item(
    const unsigned short* __restrict__ Abase,
    const unsigned short* __restrict__ Bbase,
    int ld, int nt,
    unsigned short* __restrict__ As, unsigned short* __restrict__ Bs, // each [2][8192]
    f32x4 acc[4][4], int wr, int wc, int fr, int fq)
{
    const int BUF = 128 * 64;
    stage_tile(Abase, ld, As);
    stage_tile(Bbase, ld, Bs);
    for (int t = 0; t < nt; ++t) {
        int cur = t & 1;
        if (t + 1 < nt) {
            stage_tile(Abase + (size_t)(t + 1) * BK, ld, As + (cur ^ 1) * BUF);
            stage_tile(Bbase + (size_t)(t + 1) * BK, ld, Bs + (cur ^ 1) * BUF);
            asm volatile("s_waitcnt vmcnt(8)" ::: "memory");
        } else {
            asm volatile("s_waitcnt vmcnt(0)" ::: "memory");
        }
        __builtin_amdgcn_s_barrier();      // all waves: tile t visible
        asm volatile("" ::: "memory");     // no ds_read hoist above barrier

        const unsigned short* A = As + cur * BUF;
        const unsigned short* B = Bs + cur * BUF;
        short8 a[2][4], b[2][4];
#pragma unroll
        for (int ks = 0; ks < 2; ++ks) {
            int kc = ks * 4 + fq;
#pragma unroll
            for (int m = 0; m < 4; ++m)
                a[ks][m] = *LDSF(A, wr + m * 16 + fr, kc);
#pragma unroll
            for (int n = 0; n < 4; ++n)
                b[ks][n] = *LDSF(B, wc + n * 16 + fr, kc);
        }
        __builtin_amdgcn_s_setprio(1);
#pragma unroll
        for (int ks = 0; ks < 2; ++ks)
#pragma unroll
            for (int m = 0; m < 4; ++m)
#pragma unroll
                for (int n = 0; n < 4; ++n)
                    acc[m][n] = __builtin_amdgcn_mfma_f32_16x16x32_bf16(
                        a[ks][m], b[ks][n], acc[m][n], 0, 0, 0);
        __builtin_amdgcn_s_setprio(0);
        asm volatile("s_waitcnt lgkmcnt(0)" ::: "memory");  // my buf reads done
        __builtin_amdgcn_s_barrier();                        // all waves done reading
        asm volatile("" ::: "memory");     // no next-stage hoist above barrier
    }
}

// ---------------- GEMM1: persistent work-queue, H1 = gelu(Xe@w1^T+b1) ----------------
__global__ __launch_bounds__(256, 2) void gemm1_kernel(
    const unsigned short* __restrict__ Xe, const unsigned short* __restrict__ W1b,
    const float* __restrict__ b1, unsigned short* __restrict__ H1,
    int* __restrict__ ctrl)
{
    __shared__ unsigned short As[2 * 128 * 64];
    __shared__ unsigned short Bs[2 * 128 * 64];
    __shared__ int sh_item;

    int tid = threadIdx.x, lane = tid & 63, w = tid >> 6;
    int wr = (w >> 1) * 64, wc = (w & 1) * 64;
    int fr = lane & 15, fq = lane >> 4;
    int tot = ctrl[40];

    for (;;) {
        if (tid == 0) sh_item = atomicAdd(&ctrl[26], 1);
        __syncthreads();
        int item = sh_item;
        if (item >= tot) return;

        // decode item -> (expert e, col block cb, row block rb); rb fast so
        // consecutive poppers share the same B panel (L2/L3 broadcast).
        int e = 7;
        while (item < ctrl[32 + e]) --e;
        int loc = item - ctrl[32 + e];
        int segbase = ctrl[16 + e];
        int nrb = (ctrl[17 + e] - segbase) >> 7;
        int cb = loc / nrb;
        int rb = loc - cb * nrb;
        int rowbase = segbase + (rb << 7);
        int colbase = cb << 7;

        const unsigned short* Abase = Xe + (size_t)rowbase * DD;
        const unsigned short* Bbase = W1b + (size_t)e * HH * DD + (size_t)colbase * DD;

        f32x4 acc[4][4];
#pragma unroll
        for (int m = 0; m < 4; ++m)
#pragma unroll
            for (int n = 0; n < 4; ++n) acc[m][n] = (f32x4){0.f, 0.f, 0.f, 0.f};

        gemm_item(Abase, Bbase, DD, DD / BK, As, Bs, acc, wr, wc, fr, fq);

#pragma unroll
        for (int m = 0; m < 4; ++m) {
            int row0 = rowbase + wr + m * 16 + fq * 4;
#pragma unroll
            for (int n = 0; n < 4; ++n) {
                int col = colbase + wc + n * 16 + fr;
                float bb = b1[e * HH + col];
#pragma unroll
                for (int r = 0; r < 4; ++r) {
                    float v = acc[m][n][r] + bb;
                    v = 0.5f * v * (1.f + erff(v * 0.70710678118f));
                    H1[(size_t)(row0 + r) * HH + col] = f2bf(v);
                }
            }
        }
    }
}

// ---------------- GEMM2: persistent queue + split-K x2, Yb parts ----------------
// Each item computes a K-half: part = wpos * (A_sk @ B_sk^T + bias/2), written to
// its own Yb slab; combine sums both slabs (linear in K => exact).
__global__ __launch_bounds__(256, 2) void gemm2_kernel(
    const unsigned short* __restrict__ H1, const unsigned short* __restrict__ W2b,
    const float* __restrict__ b2, const float* __restrict__ wpos,
    float* __restrict__ Yb, int* __restrict__ ctrl, int maxP)
{
    __shared__ unsigned short As[2 * 128 * 64];
    __shared__ unsigned short Bs[2 * 128 * 64];
    __shared__ int sh_item;

    int tid = threadIdx.x, lane = tid & 63, w = tid >> 6;
    int wr = (w >> 1) * 64, wc = (w & 1) * 64;
    int fr = lane & 15, fq = lane >> 4;
    int tot = ctrl[49];
    size_t Ysz = (size_t)maxP * DD;

    for (;;) {
        if (tid == 0) sh_item = atomicAdd(&ctrl[27], 1);
        __syncthreads();
        int item = sh_item;
        if (item >= tot) return;

        int e = 7;
        while (item < ctrl[41 + e]) --e;
        int loc = item - ctrl[41 + e];
        int segbase = ctrl[16 + e];
        int nrb = (ctrl[17 + e] - segbase) >> 7;
        int tmp = loc / nrb;            // (cb, sk) outer, rb inner
        int rb = loc - tmp * nrb;
        int sk = tmp & 1;
        int cb = tmp >> 1;
        int rowbase = segbase + (rb << 7);
        int colbase = cb << 7;

        const unsigned short* Abase = H1 + (size_t)rowbase * HH + sk * (HH / 2);
        const unsigned short* Bbase = W2b + (size_t)e * DD * HH + (size_t)colbase * HH + sk * (HH / 2);

        f32x4 acc[4][4];
#pragma unroll
        for (int m = 0; m < 4; ++m)
#pragma unroll
            for (int n = 0; n < 4; ++n) acc[m][n] = (f32x4){0.f, 0.f, 0.f, 0.f};

        gemm_item(Abase, Bbase, HH, HH / BK / SK2, As, Bs, acc, wr, wc, fr, fq);

        float* Yp = Yb + (size_t)sk * Ysz;
#pragma unroll
        for (int m = 0; m < 4; ++m) {
            int row0 = rowbase + wr + m * 16 + fq * 4;
            float wp[4];
#pragma unroll
            for (int r = 0; r < 4; ++r) wp[r] = wpos[row0 + r];
#pragma unroll
            for (int n = 0; n < 4; ++n) {
                int col = colbase + wc + n * 16 + fr;
                float bb = 0.5f * b2[e * DD + col];
#pragma unroll
                for (int r = 0; r < 4; ++r) {
                    float v = acc[m][n][r] + bb;
                    Yp[(size_t)(row0 + r) * DD + col] = wp[r] * v;
                }
            }
        }
    }
}

// ---------------- combine: out[t] = sum over {pos0,pos1} x {sk0,sk1} ----------------
__global__ __launch_bounds__(256) void combine_kernel(
    const float* __restrict__ Yb, const int* __restrict__ pos_of,
    const float* __restrict__ bias, float* __restrict__ out, int T, int maxP)
{
    int i = blockIdx.x * blockDim.x + threadIdx.x;
    int total = T * (DD / 4);
    size_t Ysz = (size_t)maxP * DD;
    if (i < total) {
        int t = i / (DD / 4);
        int c = (i % (DD / 4)) * 4;
        int p0 = pos_of[2 * t], p1 = pos_of[2 * t + 1];
        float4 v00 = *reinterpret_cast<const float4*>(&Yb[(size_t)p0 * DD + c]);
        float4 v01 = *reinterpret_cast<const float4*>(&Yb[Ysz + (size_t)p0 * DD + c]);
        float4 v10 = *reinterpret_cast<const float4*>(&Yb[(size_t)p1 * DD + c]);
        float4 v11 = *reinterpret_cast<const float4*>(&Yb[Ysz + (size_t)p1 * DD + c]);
        float4 o;
        o.x = v00.x + v01.x + v10.x + v11.x;
        o.y = v00.y + v01.y + v10.y + v11.y;
        o.z = v00.z + v01.z + v10.z + v11.z;
        o.w = v00.w + v01.w + v10.w + v11.w;
        *reinterpret_cast<float4*>(&out[(size_t)t * DD + c]) = o;
    } else if (i < total + DD / 4) {
        int c = (i - total) * 4;
        *reinterpret_cast<float4*>(&out[(size_t)T * DD + c]) =
            *reinterpret_cast<const float4*>(&bias[c]);
    }
}

extern "C" void kernel_launch(void* const* d_in, const int* in_sizes, int n_in,
                              void* d_out, int out_size, void* d_ws, size_t ws_size,
                              hipStream_t stream)
{
    const float* x    = (const float*)d_in[0];
    const float* gw   = (const float*)d_in[1];
    const float* gb   = (const float*)d_in[2];
    const float* w1   = (const float*)d_in[3];
    const float* b1   = (const float*)d_in[4];
    const float* w2   = (const float*)d_in[5];
    const float* b2   = (const float*)d_in[6];
    const float* bias = (const float*)d_in[7];
    float* out = (float*)d_out;

    int T = in_sizes[0] / DD;
    int nA = T * TOPK;
    int maxP = nA + NE * 128;

    char* ws = (char*)d_ws;
    size_t off = 0;
    auto alloc = [&](size_t bytes) -> char* {
        char* p = ws + off;
        off += (bytes + 255) & ~(size_t)255;
        return p;
    };
    unsigned short* w1b = (unsigned short*)alloc((size_t)NE * HH * DD * 2);
    unsigned short* w2b = (unsigned short*)alloc((size_t)NE * DD * HH * 2);
    unsigned short* Xe  = (unsigned short*)alloc((size_t)maxP * DD * 2);
    unsigned short* H1  = (unsigned short*)alloc((size_t)maxP * HH * 2);
    float*  Yb          = (float*)alloc((size_t)SK2 * maxP * DD * 4);
    int*    topk_idx    = (int*)alloc((size_t)nA * 4);
    float*  topk_w      = (float*)alloc((size_t)nA * 4);
    int*    pos_of      = (int*)alloc((size_t)nA * 4);
    float*  wpos        = (float*)alloc((size_t)maxP * 4);
    int*    token_map   = (int*)alloc((size_t)maxP * 4);
    int*    ctrl        = (int*)alloc(64 * 4);

    size_t nW = (size_t)NE * HH * DD;

    hipLaunchKernelGGL(convert_kernel, dim3(4096), dim3(256), 0, stream,
                       w1, w2, w1b, w2b, nW);
    hipLaunchKernelGGL(init_kernel, dim3((maxP + 255) / 256), dim3(256), 0, stream,
                       token_map, ctrl, maxP);
    hipLaunchKernelGGL(gate_kernel, dim3((T + 3) / 4), dim3(256), 0, stream,
                       x, gw, gb, topk_idx, topk_w, ctrl, T);
    hipLaunchKernelGGL(offsets_kernel, dim3(1), dim3(64), 0, stream, ctrl);
    hipLaunchKernelGGL(scatter_kernel, dim3((nA + 255) / 256), dim3(256), 0, stream,
                       topk_idx, topk_w, ctrl, token_map, pos_of, wpos, nA);
    hipLaunchKernelGGL(gather_kernel, dim3((maxP * (DD / 4) + 255) / 256), dim3(256), 0, stream,
                       x, token_map, Xe, maxP);
    hipLaunchKernelGGL(gemm1_kernel, dim3(512), dim3(256), 0, stream,
                       Xe, w1b, b1, H1, ctrl);
    hipLaunchKernelGGL(gemm2_kernel, dim3(512), dim3(256), 0, stream,
                       H1, w2b, b2, wpos, Yb, ctrl, maxP);
    hipLaunchKernelGGL(combine_kernel, dim3((T * (DD / 4) + DD / 4 + 255) / 256, 1, 1), dim3(256), 0, stream,
                       Yb, pos_of, bias, out, T, maxP);
}

// Round 7
// 352.149 us; speedup vs baseline: 1.8461x; 1.1317x over previous
//
#include <hip/hip_runtime.h>
#include <hip/hip_bf16.h>

#define DD 768
#define HH 3072
#define NE 8
#define TOPK 2

#define BK 64
#define NB1 (HH / 128)   // 24 col blocks, gemm1
#define NB2 (DD / 128)   // 6 col blocks, gemm2
#define SK2 2            // gemm2 K-split factor

typedef __attribute__((ext_vector_type(8))) short short8;
typedef __attribute__((ext_vector_type(4))) float f32x4;

static __device__ __forceinline__ unsigned short f2bf(float v) {
    __hip_bfloat16 b = __float2bfloat16(v);
    return *reinterpret_cast<unsigned short*>(&b);
}

// exact-GELU via A&S 7.1.26 rational erf (|err|<=1.5e-7, far below H1's bf16
// quantization). ~15 VALU ops, branchless, vs libm erff's ~30-40.
static __device__ __forceinline__ float gelu_f(float v) {
    float s = v * 0.70710678118f;
    float a = fabsf(s);
    float t = __builtin_amdgcn_rcpf(1.f + 0.3275911f * a);
    float poly = t * (0.254829592f + t * (-0.284496736f + t * (1.421413741f +
                 t * (-1.453152027f + t * 1.061405429f))));
    float erfv = 1.f - poly * __expf(-s * s);
    erfv = copysignf(erfv, s);
    return 0.5f * v * (1.f + erfv);
}

// ---------------- weight conversion fp32 -> bf16 ----------------
__global__ __launch_bounds__(256) void convert_kernel(
    const float* __restrict__ w1, const float* __restrict__ w2,
    unsigned short* __restrict__ w1b, unsigned short* __restrict__ w2b, size_t n)
{
    size_t tid = (size_t)blockIdx.x * blockDim.x + threadIdx.x;
    size_t stride = (size_t)gridDim.x * blockDim.x;
    size_t quarter = n / 4;            // float4 count per tensor
    size_t tot = 2 * quarter;
    for (size_t j = tid; j < tot; j += stride) {
        const float* src; unsigned short* dst; size_t off;
        if (j < quarter) { src = w1; dst = w1b; off = j * 4; }
        else             { src = w2; dst = w2b; off = (j - quarter) * 4; }
        float4 v = *reinterpret_cast<const float4*>(&src[off]);
        ushort4 o;
        o.x = f2bf(v.x); o.y = f2bf(v.y); o.z = f2bf(v.z); o.w = f2bf(v.w);
        *reinterpret_cast<ushort4*>(&dst[off]) = o;
    }
}

// ---------------- init control block + token_map ----------------
// ctrl: [0..8) counts | [8..16) scatter cursors | [16..25) row offsets |
//       [26] g1 item cursor | [27] g2 item cursor |
//       [32..41) g1 item prefix | [41..50) g2 item prefix
__global__ __launch_bounds__(256) void init_kernel(int* token_map, int* ctrl, int maxP)
{
    int i = blockIdx.x * blockDim.x + threadIdx.x;
    if (i < maxP) token_map[i] = -1;
    if (i < 64) ctrl[i] = 0;
}

// ---------------- gate: logits, top-2, softmax ----------------
__global__ __launch_bounds__(256) void gate_kernel(
    const float* __restrict__ x, const float* __restrict__ gw, const float* __restrict__ gb,
    int* __restrict__ topk_idx, float* __restrict__ topk_w, int* __restrict__ ctrl, int T)
{
    int t = blockIdx.x * 4 + (threadIdx.x >> 6);
    int lane = threadIdx.x & 63;
    if (t >= T) return;
    float acc[NE];
#pragma unroll
    for (int e = 0; e < NE; ++e) acc[e] = 0.f;
    const float* xr = x + (size_t)t * DD;
    for (int d = lane; d < DD; d += 64) {
        float xv = xr[d];
#pragma unroll
        for (int e = 0; e < NE; ++e) acc[e] += xv * gw[e * DD + d];
    }
#pragma unroll
    for (int e = 0; e < NE; ++e) {
        float v = acc[e];
        for (int off = 32; off; off >>= 1) v += __shfl_xor(v, off, 64);
        acc[e] = v;
    }
    if (lane == 0) {
        float lg[NE];
#pragma unroll
        for (int e = 0; e < NE; ++e) lg[e] = acc[e] + gb[e];
        int i0 = 0;
#pragma unroll
        for (int e = 1; e < NE; ++e) if (lg[e] > lg[i0]) i0 = e;
        int i1 = -1;
#pragma unroll
        for (int e = 0; e < NE; ++e) {
            if (e == i0) continue;
            if (i1 < 0 || lg[e] > lg[i1]) i1 = e;
        }
        float m = lg[i0];
        float e0 = __expf(lg[i0] - m), e1 = __expf(lg[i1] - m);
        float s = e0 + e1;
        topk_idx[2 * t]     = i0;
        topk_idx[2 * t + 1] = i1;
        topk_w[2 * t]       = e0 / s;
        topk_w[2 * t + 1]   = e1 / s;
        atomicAdd(&ctrl[i0], 1);
        atomicAdd(&ctrl[i1], 1);
    }
}

// ---------------- offsets + work-item enumeration ----------------
__global__ void offsets_kernel(int* ctrl)
{
    if (threadIdx.x == 0 && blockIdx.x == 0) {
        int acc = 0, it1 = 0, it2 = 0;
        for (int e = 0; e < NE; ++e) {
            ctrl[16 + e] = acc;
            int nrb = (ctrl[e] + 127) >> 7;        // active 128-row blocks
            acc += nrb << 7;
            ctrl[32 + e] = it1; it1 += nrb * NB1;
            ctrl[41 + e] = it2; it2 += nrb * NB2 * SK2;
        }
        ctrl[24] = acc;      // total padded rows
        ctrl[40] = it1;      // total gemm1 items
        ctrl[49] = it2;      // total gemm2 items
    }
}

// ---------------- scatter assignments to expert segments ----------------
__global__ __launch_bounds__(256) void scatter_kernel(
    const int* __restrict__ topk_idx, const float* __restrict__ topk_w,
    int* ctrl, int* token_map, int* pos_of, float* wpos, int nA)
{
    int a = blockIdx.x * blockDim.x + threadIdx.x;
    if (a >= nA) return;
    int e = topk_idx[a];
    int p = ctrl[16 + e] + atomicAdd(&ctrl[8 + e], 1);
    token_map[p] = a;
    pos_of[a] = p;
    wpos[p] = topk_w[a];
}

// ---------------- gather x rows -> bf16 Xe ----------------
__global__ __launch_bounds__(256) void gather_kernel(
    const float* __restrict__ x, const int* __restrict__ token_map,
    unsigned short* __restrict__ Xe, int maxP)
{
    int i = blockIdx.x * blockDim.x + threadIdx.x;
    int total = maxP * (DD / 4);
    if (i >= total) return;
    int r = i / (DD / 4);
    int c = (i % (DD / 4)) * 4;
    int a = token_map[r];
    ushort4 o;
    if (a < 0) {
        o.x = o.y = o.z = o.w = 0;
    } else {
        float4 v = *reinterpret_cast<const float4*>(&x[(size_t)(a >> 1) * DD + c]);
        o.x = f2bf(v.x); o.y = f2bf(v.y); o.z = f2bf(v.z); o.w = f2bf(v.w);
    }
    *reinterpret_cast<ushort4*>(&Xe[(size_t)r * DD + c]) = o;
}

// ---------------- staging: 128 rows x 64 cols bf16 tile -> LDS ----------------
// Linear LDS dest + inverse-XOR-swizzled per-lane global source (verified: 0 conflicts).
// Chunk (row,kc) lives at LDS chunk row*8 + (kc ^ (row&7)); reader applies same XOR.
static __device__ __forceinline__ void stage_tile(
    const unsigned short* __restrict__ g, int ld, unsigned short* __restrict__ lds)
{
    int tid = threadIdx.x;   // 256 threads, 4 chunks each
#pragma unroll
    for (int r = 0; r < 4; ++r) {
        int j = (r << 8) + tid;           // chunk idx 0..1023
        int row = j >> 3;
        int kc = (j & 7) ^ (row & 7);     // inverse swizzle on SOURCE
        __builtin_amdgcn_global_load_lds(
            (const __attribute__((address_space(1))) void*)(g + (size_t)row * ld + (kc << 3)),
            (__attribute__((address_space(3))) void*)(lds + (j << 3)),
            16, 0, 0);
    }
}

#define LDSF(base, row, kc) \
    reinterpret_cast<const short8*>(&(base)[((((row) << 3) + ((kc) ^ ((row) & 7))) << 3)])

// ---------------- dbuf K-loop with counted vmcnt (never drained in-loop) ----------------
// Iter t: issue stage(t+1 -> buf^1); s_waitcnt vmcnt(8) => tile t landed, tile t+1's
// 8 loads stay in flight across the barrier; raw s_barrier; ds_read+32 MFMA;
// lgkmcnt(0); raw s_barrier. OPERANDS SWAPPED in the MFMA: acc = mfma(b, a, acc)
// puts the C/D fragment's 4 per-lane values along the OUTPUT-CHANNEL dim, enabling
// ushort4/float4 epilogue stores (4x fewer VMEM store instructions).
static __device__ __forceinline__ void gemm_item(
    const unsigned short* __restrict__ Abase,
    const unsigned short* __restrict__ Bbase,
    int ld, int nt,
    unsigned short* __restrict__ As, unsigned short* __restrict__ Bs, // each [2][8192]
    f32x4 acc[4][4], int wr, int wc, int fr, int fq)
{
    const int BUF = 128 * 64;
    stage_tile(Abase, ld, As);
    stage_tile(Bbase, ld, Bs);
    for (int t = 0; t < nt; ++t) {
        int cur = t & 1;
        if (t + 1 < nt) {
            stage_tile(Abase + (size_t)(t + 1) * BK, ld, As + (cur ^ 1) * BUF);
            stage_tile(Bbase + (size_t)(t + 1) * BK, ld, Bs + (cur ^ 1) * BUF);
            asm volatile("s_waitcnt vmcnt(8)" ::: "memory");
        } else {
            asm volatile("s_waitcnt vmcnt(0)" ::: "memory");
        }
        __builtin_amdgcn_s_barrier();      // all waves: tile t visible
        asm volatile("" ::: "memory");     // no ds_read hoist above barrier

        const unsigned short* A = As + cur * BUF;
        const unsigned short* B = Bs + cur * BUF;
        short8 a[2][4], b[2][4];
#pragma unroll
        for (int ks = 0; ks < 2; ++ks) {
            int kc = ks * 4 + fq;
#pragma unroll
            for (int m = 0; m < 4; ++m)
                a[ks][m] = *LDSF(A, wr + m * 16 + fr, kc);
#pragma unroll
            for (int n = 0; n < 4; ++n)
                b[ks][n] = *LDSF(B, wc + n * 16 + fr, kc);
        }
        __builtin_amdgcn_s_setprio(1);
#pragma unroll
        for (int ks = 0; ks < 2; ++ks)
#pragma unroll
            for (int m = 0; m < 4; ++m)
#pragma unroll
                for (int n = 0; n < 4; ++n)
                    acc[m][n] = __builtin_amdgcn_mfma_f32_16x16x32_bf16(
                        b[ks][n], a[ks][m], acc[m][n], 0, 0, 0);   // SWAPPED
        __builtin_amdgcn_s_setprio(0);
        asm volatile("s_waitcnt lgkmcnt(0)" ::: "memory");  // my buf reads done
        __builtin_amdgcn_s_barrier();                        // all waves done reading
        asm volatile("" ::: "memory");     // no next-stage hoist above barrier
    }
}

// After the swap, acc[m][n] holds D[ch][tok]: ch = colbase+wc+n*16+fq*4+r (r=reg),
// tok = rowbase+wr+m*16+fr. Per lane per (m,n): 4 CONSECUTIVE channels of one token.

// ---------------- GEMM1: persistent work-queue, H1 = gelu(Xe@w1^T+b1) ----------------
__global__ __launch_bounds__(256, 2) void gemm1_kernel(
    const unsigned short* __restrict__ Xe, const unsigned short* __restrict__ W1b,
    const float* __restrict__ b1, unsigned short* __restrict__ H1,
    int* __restrict__ ctrl)
{
    __shared__ unsigned short As[2 * 128 * 64];
    __shared__ unsigned short Bs[2 * 128 * 64];
    __shared__ int sh_item;
    __shared__ int seg[9], ipfx[9];       // cached ctrl prefixes (kills per-item
                                           // global pointer-chase in decode)
    int tid = threadIdx.x;
    if (tid < 9) { seg[tid] = ctrl[16 + tid]; ipfx[tid] = ctrl[32 + tid]; }
    __syncthreads();

    int lane = tid & 63, w = tid >> 6;
    int wr = (w >> 1) * 64, wc = (w & 1) * 64;
    int fr = lane & 15, fq = lane >> 4;
    int tot = ipfx[8];

    for (;;) {
        if (tid == 0) sh_item = atomicAdd(&ctrl[26], 1);
        __syncthreads();
        int item = sh_item;
        if (item >= tot) return;

        // decode item -> (expert e, col block cb, row block rb); rb fast so
        // consecutive poppers share the same B panel (L2/L3 broadcast).
        int e = 7;
        while (item < ipfx[e]) --e;
        int loc = item - ipfx[e];
        int segbase = seg[e];
        int nrb = (seg[e + 1] - segbase) >> 7;
        int cb = loc / nrb;
        int rb = loc - cb * nrb;
        int rowbase = segbase + (rb << 7);
        int colbase = cb << 7;

        const unsigned short* Abase = Xe + (size_t)rowbase * DD;
        const unsigned short* Bbase = W1b + (size_t)e * HH * DD + (size_t)colbase * DD;

        f32x4 acc[4][4];
#pragma unroll
        for (int m = 0; m < 4; ++m)
#pragma unroll
            for (int n = 0; n < 4; ++n) acc[m][n] = (f32x4){0.f, 0.f, 0.f, 0.f};

        gemm_item(Abase, Bbase, DD, DD / BK, As, Bs, acc, wr, wc, fr, fq);

        // epilogue: 4 float4 bias loads + 16 ushort4 stores per thread
        float4 bb[4];
#pragma unroll
        for (int n = 0; n < 4; ++n)
            bb[n] = *reinterpret_cast<const float4*>(
                &b1[e * HH + colbase + wc + n * 16 + fq * 4]);
#pragma unroll
        for (int m = 0; m < 4; ++m) {
            int tok = rowbase + wr + m * 16 + fr;
#pragma unroll
            for (int n = 0; n < 4; ++n) {
                int ch = colbase + wc + n * 16 + fq * 4;
                ushort4 o;
                o.x = f2bf(gelu_f(acc[m][n][0] + bb[n].x));
                o.y = f2bf(gelu_f(acc[m][n][1] + bb[n].y));
                o.z = f2bf(gelu_f(acc[m][n][2] + bb[n].z));
                o.w = f2bf(gelu_f(acc[m][n][3] + bb[n].w));
                *reinterpret_cast<ushort4*>(&H1[(size_t)tok * HH + ch]) = o;
            }
        }
    }
}

// ---------------- GEMM2: persistent queue + split-K x2, Yb parts ----------------
// Each item computes a K-half: part = wpos * (A_sk @ B_sk^T + bias/2), written to
// its own Yb slab; combine sums both slabs (linear in K => exact).
__global__ __launch_bounds__(256, 2) void gemm2_kernel(
    const unsigned short* __restrict__ H1, const unsigned short* __restrict__ W2b,
    const float* __restrict__ b2, const float* __restrict__ wpos,
    float* __restrict__ Yb, int* __restrict__ ctrl, int maxP)
{
    __shared__ unsigned short As[2 * 128 * 64];
    __shared__ unsigned short Bs[2 * 128 * 64];
    __shared__ int sh_item;
    __shared__ int seg[9], ipfx[9];
    int tid = threadIdx.x;
    if (tid < 9) { seg[tid] = ctrl[16 + tid]; ipfx[tid] = ctrl[41 + tid]; }
    __syncthreads();

    int lane = tid & 63, w = tid >> 6;
    int wr = (w >> 1) * 64, wc = (w & 1) * 64;
    int fr = lane & 15, fq = lane >> 4;
    int tot = ipfx[8];
    size_t Ysz = (size_t)maxP * DD;

    for (;;) {
        if (tid == 0) sh_item = atomicAdd(&ctrl[27], 1);
        __syncthreads();
        int item = sh_item;
        if (item >= tot) return;

        int e = 7;
        while (item < ipfx[e]) --e;
        int loc = item - ipfx[e];
        int segbase = seg[e];
        int nrb = (seg[e + 1] - segbase) >> 7;
        int tmp = loc / nrb;            // (cb, sk) outer, rb inner
        int rb = loc - tmp * nrb;
        int sk = tmp & 1;
        int cb = tmp >> 1;
        int rowbase = segbase + (rb << 7);
        int colbase = cb << 7;

        const unsigned short* Abase = H1 + (size_t)rowbase * HH + sk * (HH / 2);
        const unsigned short* Bbase = W2b + (size_t)e * DD * HH + (size_t)colbase * HH + sk * (HH / 2);

        f32x4 acc[4][4];
#pragma unroll
        for (int m = 0; m < 4; ++m)
#pragma unroll
            for (int n = 0; n < 4; ++n) acc[m][n] = (f32x4){0.f, 0.f, 0.f, 0.f};

        gemm_item(Abase, Bbase, HH, HH / BK / SK2, As, Bs, acc, wr, wc, fr, fq);

        float* Yp = Yb + (size_t)sk * Ysz;
        float4 bb[4];
#pragma unroll
        for (int n = 0; n < 4; ++n) {
            float4 b4 = *reinterpret_cast<const float4*>(
                &b2[e * DD + colbase + wc + n * 16 + fq * 4]);
            bb[n].x = 0.5f * b4.x; bb[n].y = 0.5f * b4.y;
            bb[n].z = 0.5f * b4.z; bb[n].w = 0.5f * b4.w;
        }
#pragma unroll
        for (int m = 0; m < 4; ++m) {
            int tok = rowbase + wr + m * 16 + fr;
            float wp = wpos[tok];
#pragma unroll
            for (int n = 0; n < 4; ++n) {
                int ch = colbase + wc + n * 16 + fq * 4;
                float4 o;
                o.x = wp * (acc[m][n][0] + bb[n].x);
                o.y = wp * (acc[m][n][1] + bb[n].y);
                o.z = wp * (acc[m][n][2] + bb[n].z);
                o.w = wp * (acc[m][n][3] + bb[n].w);
                *reinterpret_cast<float4*>(&Yp[(size_t)tok * DD + ch]) = o;
            }
        }
    }
}

// ---------------- combine: out[t] = sum over {pos0,pos1} x {sk0,sk1} ----------------
__global__ __launch_bounds__(256) void combine_kernel(
    const float* __restrict__ Yb, const int* __restrict__ pos_of,
    const float* __restrict__ bias, float* __restrict__ out, int T, int maxP)
{
    int i = blockIdx.x * blockDim.x + threadIdx.x;
    int total = T * (DD / 4);
    size_t Ysz = (size_t)maxP * DD;
    if (i < total) {
        int t = i / (DD / 4);
        int c = (i % (DD / 4)) * 4;
        int p0 = pos_of[2 * t], p1 = pos_of[2 * t + 1];
        float4 v00 = *reinterpret_cast<const float4*>(&Yb[(size_t)p0 * DD + c]);
        float4 v01 = *reinterpret_cast<const float4*>(&Yb[Ysz + (size_t)p0 * DD + c]);
        float4 v10 = *reinterpret_cast<const float4*>(&Yb[(size_t)p1 * DD + c]);
        float4 v11 = *reinterpret_cast<const float4*>(&Yb[Ysz + (size_t)p1 * DD + c]);
        float4 o;
        o.x = v00.x + v01.x + v10.x + v11.x;
        o.y = v00.y + v01.y + v10.y + v11.y;
        o.z = v00.z + v01.z + v10.z + v11.z;
        o.w = v00.w + v01.w + v10.w + v11.w;
        *reinterpret_cast<float4*>(&out[(size_t)t * DD + c]) = o;
    } else if (i < total + DD / 4) {
        int c = (i - total) * 4;
        *reinterpret_cast<float4*>(&out[(size_t)T * DD + c]) =
            *reinterpret_cast<const float4*>(&bias[c]);
    }
}

extern "C" void kernel_launch(void* const* d_in, const int* in_sizes, int n_in,
                              void* d_out, int out_size, void* d_ws, size_t ws_size,
                              hipStream_t stream)
{
    const float* x    = (const float*)d_in[0];
    const float* gw   = (const float*)d_in[1];
    const float* gb   = (const float*)d_in[2];
    const float* w1   = (const float*)d_in[3];
    const float* b1   = (const float*)d_in[4];
    const float* w2   = (const float*)d_in[5];
    const float* b2   = (const float*)d_in[6];
    const float* bias = (const float*)d_in[7];
    float* out = (float*)d_out;

    int T = in_sizes[0] / DD;
    int nA = T * TOPK;
    int maxP = nA + NE * 128;

    char* ws = (char*)d_ws;
    size_t off = 0;
    auto alloc = [&](size_t bytes) -> char* {
        char* p = ws + off;
        off += (bytes + 255) & ~(size_t)255;
        return p;
    };
    unsigned short* w1b = (unsigned short*)alloc((size_t)NE * HH * DD * 2);
    unsigned short* w2b = (unsigned short*)alloc((size_t)NE * DD * HH * 2);
    unsigned short* Xe  = (unsigned short*)alloc((size_t)maxP * DD * 2);
    unsigned short* H1  = (unsigned short*)alloc((size_t)maxP * HH * 2);
    float*  Yb          = (float*)alloc((size_t)SK2 * maxP * DD * 4);
    int*    topk_idx    = (int*)alloc((size_t)nA * 4);
    float*  topk_w      = (float*)alloc((size_t)nA * 4);
    int*    pos_of      = (int*)alloc((size_t)nA * 4);
    float*  wpos        = (float*)alloc((size_t)maxP * 4);
    int*    token_map   = (int*)alloc((size_t)maxP * 4);
    int*    ctrl        = (int*)alloc(64 * 4);

    size_t nW = (size_t)NE * HH * DD;

    hipLaunchKernelGGL(convert_kernel, dim3(4096), dim3(256), 0, stream,
                       w1, w2, w1b, w2b, nW);
    hipLaunchKernelGGL(init_kernel, dim3((maxP + 255) / 256), dim3(256), 0, stream,
                       token_map, ctrl, maxP);
    hipLaunchKernelGGL(gate_kernel, dim3((T + 3) / 4), dim3(256), 0, stream,
                       x, gw, gb, topk_idx, topk_w, ctrl, T);
    hipLaunchKernelGGL(offsets_kernel, dim3(1), dim3(64), 0, stream, ctrl);
    hipLaunchKernelGGL(scatter_kernel, dim3((nA + 255) / 256), dim3(256), 0, stream,
                       topk_idx, topk_w, ctrl, token_map, pos_of, wpos, nA);
    hipLaunchKernelGGL(gather_kernel, dim3((maxP * (DD / 4) + 255) / 256), dim3(256), 0, stream,
                       x, token_map, Xe, maxP);
    hipLaunchKernelGGL(gemm1_kernel, dim3(512), dim3(256), 0, stream,
                       Xe, w1b, b1, H1, ctrl);
    hipLaunchKernelGGL(gemm2_kernel, dim3(512), dim3(256), 0, stream,
                       H1, w2b, b2, wpos, Yb, ctrl, maxP);
    hipLaunchKernelGGL(combine_kernel, dim3((T * (DD / 4) + DD / 4 + 255) / 256, 1, 1), dim3(256), 0, stream,
                       Yb, pos_of, bias, out, T, maxP);
}

// Round 8
// 234.587 us; speedup vs baseline: 2.7713x; 1.5011x over previous
//
#include <hip/hip_runtime.h>
#include <hip/hip_bf16.h>

#define DD 768
#define HH 3072
#define NE 8
#define TOPK 2

#define BK 64
#define NB1 (HH / 128)   // 24 col blocks, gemm1
#define NB2 (DD / 128)   // 6 col blocks, gemm2
#define SK2 2            // gemm2 K-split factor

typedef __attribute__((ext_vector_type(8))) short short8;
typedef __attribute__((ext_vector_type(4))) float f32x4;

static __device__ __forceinline__ unsigned short f2bf(float v) {
    __hip_bfloat16 b = __float2bfloat16(v);
    return *reinterpret_cast<unsigned short*>(&b);
}

// exact-GELU via A&S 7.1.26 rational erf (|err|<=1.5e-7, far below H1's bf16
// quantization). ~15 VALU ops, branchless, vs libm erff's ~30-40.
static __device__ __forceinline__ float gelu_f(float v) {
    float s = v * 0.70710678118f;
    float a = fabsf(s);
    float t = __builtin_amdgcn_rcpf(1.f + 0.3275911f * a);
    float poly = t * (0.254829592f + t * (-0.284496736f + t * (1.421413741f +
                 t * (-1.453152027f + t * 1.061405429f))));
    float erfv = 1.f - poly * __expf(-s * s);
    erfv = copysignf(erfv, s);
    return 0.5f * v * (1.f + erfv);
}

// ---------------- weight conversion fp32 -> bf16 ----------------
__global__ __launch_bounds__(256) void convert_kernel(
    const float* __restrict__ w1, const float* __restrict__ w2,
    unsigned short* __restrict__ w1b, unsigned short* __restrict__ w2b, size_t n)
{
    size_t tid = (size_t)blockIdx.x * blockDim.x + threadIdx.x;
    size_t stride = (size_t)gridDim.x * blockDim.x;
    size_t quarter = n / 4;            // float4 count per tensor
    size_t tot = 2 * quarter;
    for (size_t j = tid; j < tot; j += stride) {
        const float* src; unsigned short* dst; size_t off;
        if (j < quarter) { src = w1; dst = w1b; off = j * 4; }
        else             { src = w2; dst = w2b; off = (j - quarter) * 4; }
        float4 v = *reinterpret_cast<const float4*>(&src[off]);
        ushort4 o;
        o.x = f2bf(v.x); o.y = f2bf(v.y); o.z = f2bf(v.z); o.w = f2bf(v.w);
        *reinterpret_cast<ushort4*>(&dst[off]) = o;
    }
}

// ---------------- init control block + token_map ----------------
// ctrl: [0..8) counts | [8..16) scatter cursors | [16..25) row offsets |
//       [26] g1 item cursor | [27] g2 item cursor |
//       [32..41) g1 item prefix | [41..50) g2 item prefix
__global__ __launch_bounds__(256) void init_kernel(int* token_map, int* ctrl, int maxP)
{
    int i = blockIdx.x * blockDim.x + threadIdx.x;
    if (i < maxP) token_map[i] = -1;
    if (i < 64) ctrl[i] = 0;
}

// ---------------- gate: logits, top-2, softmax ----------------
// Per-block LDS histogram; ONE global atomicAdd per expert per block at the end.
// (Round 7 PMC: 16384 same-cacheline device atomics serialized = 106 us with all
// pipes idle. LDS atomics are per-CU and fast; global contention drops 8192->512/addr.)
__global__ __launch_bounds__(256) void gate_kernel(
    const float* __restrict__ x, const float* __restrict__ gw, const float* __restrict__ gb,
    int* __restrict__ topk_idx, float* __restrict__ topk_w, int* __restrict__ ctrl, int T)
{
    __shared__ int hist[NE];
    int tid = threadIdx.x;
    if (tid < NE) hist[tid] = 0;
    __syncthreads();

    int w = tid >> 6, lane = tid & 63;
    for (int t = blockIdx.x * 4 + w; t < T; t += gridDim.x * 4) {
        float acc[NE];
#pragma unroll
        for (int e = 0; e < NE; ++e) acc[e] = 0.f;
        const float* xr = x + (size_t)t * DD;
        for (int d = lane; d < DD; d += 64) {
            float xv = xr[d];
#pragma unroll
            for (int e = 0; e < NE; ++e) acc[e] += xv * gw[e * DD + d];
        }
#pragma unroll
        for (int e = 0; e < NE; ++e) {
            float v = acc[e];
            for (int off = 32; off; off >>= 1) v += __shfl_xor(v, off, 64);
            acc[e] = v;
        }
        if (lane == 0) {
            float lg[NE];
#pragma unroll
            for (int e = 0; e < NE; ++e) lg[e] = acc[e] + gb[e];
            int i0 = 0;
#pragma unroll
            for (int e = 1; e < NE; ++e) if (lg[e] > lg[i0]) i0 = e;
            int i1 = -1;
#pragma unroll
            for (int e = 0; e < NE; ++e) {
                if (e == i0) continue;
                if (i1 < 0 || lg[e] > lg[i1]) i1 = e;
            }
            float m = lg[i0];
            float e0 = __expf(lg[i0] - m), e1 = __expf(lg[i1] - m);
            float s = e0 + e1;
            topk_idx[2 * t]     = i0;
            topk_idx[2 * t + 1] = i1;
            topk_w[2 * t]       = e0 / s;
            topk_w[2 * t + 1]   = e1 / s;
            atomicAdd(&hist[i0], 1);    // LDS atomic: per-CU, fast
            atomicAdd(&hist[i1], 1);
        }
    }
    __syncthreads();
    if (tid < NE && hist[tid] > 0) atomicAdd(&ctrl[tid], hist[tid]);
}

// ---------------- offsets + work-item enumeration ----------------
__global__ void offsets_kernel(int* ctrl)
{
    if (threadIdx.x == 0 && blockIdx.x == 0) {
        int acc = 0, it1 = 0, it2 = 0;
        for (int e = 0; e < NE; ++e) {
            ctrl[16 + e] = acc;
            int nrb = (ctrl[e] + 127) >> 7;        // active 128-row blocks
            acc += nrb << 7;
            ctrl[32 + e] = it1; it1 += nrb * NB1;
            ctrl[41 + e] = it2; it2 += nrb * NB2 * SK2;
        }
        ctrl[24] = acc;      // total padded rows
        ctrl[40] = it1;      // total gemm1 items
        ctrl[49] = it2;      // total gemm2 items
    }
}

// ---------------- scatter: block-aggregated segment allocation ----------------
// LDS atomicAdd gives each assignment a unique in-block rank; one global
// atomicAdd per expert per block reserves the segment range (256 total vs 8192
// same-cacheline atomics before). Within-segment order is arbitrary (only
// uniqueness matters; combine indexes through pos_of), so this is exact.
__global__ __launch_bounds__(256) void scatter_kernel(
    const int* __restrict__ topk_idx, const float* __restrict__ topk_w,
    int* ctrl, int* token_map, int* pos_of, float* wpos, int nA)
{
    __shared__ int lh[NE], lbase[NE];
    int tid = threadIdx.x;
    if (tid < NE) lh[tid] = 0;
    __syncthreads();

    int a = blockIdx.x * blockDim.x + tid;
    int e = 0, rank = 0;
    bool valid = (a < nA);
    if (valid) {
        e = topk_idx[a];
        rank = atomicAdd(&lh[e], 1);   // LDS atomic: unique in-block rank
    }
    __syncthreads();
    if (tid < NE && lh[tid] > 0)
        lbase[tid] = atomicAdd(&ctrl[8 + tid], lh[tid]);
    __syncthreads();
    if (valid) {
        int p = ctrl[16 + e] + lbase[e] + rank;
        token_map[p] = a;
        pos_of[a] = p;
        wpos[p] = topk_w[a];
    }
}

// ---------------- gather x rows -> bf16 Xe ----------------
__global__ __launch_bounds__(256) void gather_kernel(
    const float* __restrict__ x, const int* __restrict__ token_map,
    unsigned short* __restrict__ Xe, int maxP)
{
    int i = blockIdx.x * blockDim.x + threadIdx.x;
    int total = maxP * (DD / 4);
    if (i >= total) return;
    int r = i / (DD / 4);
    int c = (i % (DD / 4)) * 4;
    int a = token_map[r];
    ushort4 o;
    if (a < 0) {
        o.x = o.y = o.z = o.w = 0;
    } else {
        float4 v = *reinterpret_cast<const float4*>(&x[(size_t)(a >> 1) * DD + c]);
        o.x = f2bf(v.x); o.y = f2bf(v.y); o.z = f2bf(v.z); o.w = f2bf(v.w);
    }
    *reinterpret_cast<ushort4*>(&Xe[(size_t)r * DD + c]) = o;
}

// ---------------- staging: 128 rows x 64 cols bf16 tile -> LDS ----------------
// Linear LDS dest + inverse-XOR-swizzled per-lane global source (verified: 0 conflicts).
// Chunk (row,kc) lives at LDS chunk row*8 + (kc ^ (row&7)); reader applies same XOR.
static __device__ __forceinline__ void stage_tile(
    const unsigned short* __restrict__ g, int ld, unsigned short* __restrict__ lds)
{
    int tid = threadIdx.x;   // 256 threads, 4 chunks each
#pragma unroll
    for (int r = 0; r < 4; ++r) {
        int j = (r << 8) + tid;           // chunk idx 0..1023
        int row = j >> 3;
        int kc = (j & 7) ^ (row & 7);     // inverse swizzle on SOURCE
        __builtin_amdgcn_global_load_lds(
            (const __attribute__((address_space(1))) void*)(g + (size_t)row * ld + (kc << 3)),
            (__attribute__((address_space(3))) void*)(lds + (j << 3)),
            16, 0, 0);
    }
}

#define LDSF(base, row, kc) \
    reinterpret_cast<const short8*>(&(base)[((((row) << 3) + ((kc) ^ ((row) & 7))) << 3)])

// ---------------- dbuf K-loop with counted vmcnt (never drained in-loop) ----------------
// Iter t: issue stage(t+1 -> buf^1); s_waitcnt vmcnt(8) => tile t landed, tile t+1's
// 8 loads stay in flight across the barrier; raw s_barrier; ds_read+32 MFMA;
// lgkmcnt(0); raw s_barrier. OPERANDS SWAPPED in the MFMA: acc = mfma(b, a, acc)
// puts the C/D fragment's 4 per-lane values along the OUTPUT-CHANNEL dim, enabling
// ushort4/float4 epilogue stores (4x fewer VMEM store instructions).
static __device__ __forceinline__ void gemm_item(
    const unsigned short* __restrict__ Abase,
    const unsigned short* __restrict__ Bbase,
    int ld, int nt,
    unsigned short* __restrict__ As, unsigned short* __restrict__ Bs, // each [2][8192]
    f32x4 acc[4][4], int wr, int wc, int fr, int fq)
{
    const int BUF = 128 * 64;
    stage_tile(Abase, ld, As);
    stage_tile(Bbase, ld, Bs);
    for (int t = 0; t < nt; ++t) {
        int cur = t & 1;
        if (t + 1 < nt) {
            stage_tile(Abase + (size_t)(t + 1) * BK, ld, As + (cur ^ 1) * BUF);
            stage_tile(Bbase + (size_t)(t + 1) * BK, ld, Bs + (cur ^ 1) * BUF);
            asm volatile("s_waitcnt vmcnt(8)" ::: "memory");
        } else {
            asm volatile("s_waitcnt vmcnt(0)" ::: "memory");
        }
        __builtin_amdgcn_s_barrier();      // all waves: tile t visible
        asm volatile("" ::: "memory");     // no ds_read hoist above barrier

        const unsigned short* A = As + cur * BUF;
        const unsigned short* B = Bs + cur * BUF;
        short8 a[2][4], b[2][4];
#pragma unroll
        for (int ks = 0; ks < 2; ++ks) {
            int kc = ks * 4 + fq;
#pragma unroll
            for (int m = 0; m < 4; ++m)
                a[ks][m] = *LDSF(A, wr + m * 16 + fr, kc);
#pragma unroll
            for (int n = 0; n < 4; ++n)
                b[ks][n] = *LDSF(B, wc + n * 16 + fr, kc);
        }
        __builtin_amdgcn_s_setprio(1);
#pragma unroll
        for (int ks = 0; ks < 2; ++ks)
#pragma unroll
            for (int m = 0; m < 4; ++m)
#pragma unroll
                for (int n = 0; n < 4; ++n)
                    acc[m][n] = __builtin_amdgcn_mfma_f32_16x16x32_bf16(
                        b[ks][n], a[ks][m], acc[m][n], 0, 0, 0);   // SWAPPED
        __builtin_amdgcn_s_setprio(0);
        asm volatile("s_waitcnt lgkmcnt(0)" ::: "memory");  // my buf reads done
        __builtin_amdgcn_s_barrier();                        // all waves done reading
        asm volatile("" ::: "memory");     // no next-stage hoist above barrier
    }
}

// After the swap, acc[m][n] holds D[ch][tok]: ch = colbase+wc+n*16+fq*4+r (r=reg),
// tok = rowbase+wr+m*16+fr. Per lane per (m,n): 4 CONSECUTIVE channels of one token.

// ---------------- GEMM1: persistent work-queue, H1 = gelu(Xe@w1^T+b1) ----------------
__global__ __launch_bounds__(256, 2) void gemm1_kernel(
    const unsigned short* __restrict__ Xe, const unsigned short* __restrict__ W1b,
    const float* __restrict__ b1, unsigned short* __restrict__ H1,
    int* __restrict__ ctrl)
{
    __shared__ unsigned short As[2 * 128 * 64];
    __shared__ unsigned short Bs[2 * 128 * 64];
    __shared__ int sh_item;
    __shared__ int seg[9], ipfx[9];       // cached ctrl prefixes (kills per-item
                                           // global pointer-chase in decode)
    int tid = threadIdx.x;
    if (tid < 9) { seg[tid] = ctrl[16 + tid]; ipfx[tid] = ctrl[32 + tid]; }
    __syncthreads();

    int lane = tid & 63, w = tid >> 6;
    int wr = (w >> 1) * 64, wc = (w & 1) * 64;
    int fr = lane & 15, fq = lane >> 4;
    int tot = ipfx[8];

    for (;;) {
        if (tid == 0) sh_item = atomicAdd(&ctrl[26], 1);
        __syncthreads();
        int item = sh_item;
        if (item >= tot) return;

        // decode item -> (expert e, col block cb, row block rb); rb fast so
        // consecutive poppers share the same B panel (L2/L3 broadcast).
        int e = 7;
        while (item < ipfx[e]) --e;
        int loc = item - ipfx[e];
        int segbase = seg[e];
        int nrb = (seg[e + 1] - segbase) >> 7;
        int cb = loc / nrb;
        int rb = loc - cb * nrb;
        int rowbase = segbase + (rb << 7);
        int colbase = cb << 7;

        const unsigned short* Abase = Xe + (size_t)rowbase * DD;
        const unsigned short* Bbase = W1b + (size_t)e * HH * DD + (size_t)colbase * DD;

        f32x4 acc[4][4];
#pragma unroll
        for (int m = 0; m < 4; ++m)
#pragma unroll
            for (int n = 0; n < 4; ++n) acc[m][n] = (f32x4){0.f, 0.f, 0.f, 0.f};

        gemm_item(Abase, Bbase, DD, DD / BK, As, Bs, acc, wr, wc, fr, fq);

        // epilogue: 4 float4 bias loads + 16 ushort4 stores per thread
        float4 bb[4];
#pragma unroll
        for (int n = 0; n < 4; ++n)
            bb[n] = *reinterpret_cast<const float4*>(
                &b1[e * HH + colbase + wc + n * 16 + fq * 4]);
#pragma unroll
        for (int m = 0; m < 4; ++m) {
            int tok = rowbase + wr + m * 16 + fr;
#pragma unroll
            for (int n = 0; n < 4; ++n) {
                int ch = colbase + wc + n * 16 + fq * 4;
                ushort4 o;
                o.x = f2bf(gelu_f(acc[m][n][0] + bb[n].x));
                o.y = f2bf(gelu_f(acc[m][n][1] + bb[n].y));
                o.z = f2bf(gelu_f(acc[m][n][2] + bb[n].z));
                o.w = f2bf(gelu_f(acc[m][n][3] + bb[n].w));
                *reinterpret_cast<ushort4*>(&H1[(size_t)tok * HH + ch]) = o;
            }
        }
    }
}

// ---------------- GEMM2: persistent queue + split-K x2, Yb parts ----------------
// Each item computes a K-half: part = wpos * (A_sk @ B_sk^T + bias/2), written to
// its own Yb slab; combine sums both slabs (linear in K => exact).
__global__ __launch_bounds__(256, 2) void gemm2_kernel(
    const unsigned short* __restrict__ H1, const unsigned short* __restrict__ W2b,
    const float* __restrict__ b2, const float* __restrict__ wpos,
    float* __restrict__ Yb, int* __restrict__ ctrl, int maxP)
{
    __shared__ unsigned short As[2 * 128 * 64];
    __shared__ unsigned short Bs[2 * 128 * 64];
    __shared__ int sh_item;
    __shared__ int seg[9], ipfx[9];
    int tid = threadIdx.x;
    if (tid < 9) { seg[tid] = ctrl[16 + tid]; ipfx[tid] = ctrl[41 + tid]; }
    __syncthreads();

    int lane = tid & 63, w = tid >> 6;
    int wr = (w >> 1) * 64, wc = (w & 1) * 64;
    int fr = lane & 15, fq = lane >> 4;
    int tot = ipfx[8];
    size_t Ysz = (size_t)maxP * DD;

    for (;;) {
        if (tid == 0) sh_item = atomicAdd(&ctrl[27], 1);
        __syncthreads();
        int item = sh_item;
        if (item >= tot) return;

        int e = 7;
        while (item < ipfx[e]) --e;
        int loc = item - ipfx[e];
        int segbase = seg[e];
        int nrb = (seg[e + 1] - segbase) >> 7;
        int tmp = loc / nrb;            // (cb, sk) outer, rb inner
        int rb = loc - tmp * nrb;
        int sk = tmp & 1;
        int cb = tmp >> 1;
        int rowbase = segbase + (rb << 7);
        int colbase = cb << 7;

        const unsigned short* Abase = H1 + (size_t)rowbase * HH + sk * (HH / 2);
        const unsigned short* Bbase = W2b + (size_t)e * DD * HH + (size_t)colbase * HH + sk * (HH / 2);

        f32x4 acc[4][4];
#pragma unroll
        for (int m = 0; m < 4; ++m)
#pragma unroll
            for (int n = 0; n < 4; ++n) acc[m][n] = (f32x4){0.f, 0.f, 0.f, 0.f};

        gemm_item(Abase, Bbase, HH, HH / BK / SK2, As, Bs, acc, wr, wc, fr, fq);

        float* Yp = Yb + (size_t)sk * Ysz;
        float4 bb[4];
#pragma unroll
        for (int n = 0; n < 4; ++n) {
            float4 b4 = *reinterpret_cast<const float4*>(
                &b2[e * DD + colbase + wc + n * 16 + fq * 4]);
            bb[n].x = 0.5f * b4.x; bb[n].y = 0.5f * b4.y;
            bb[n].z = 0.5f * b4.z; bb[n].w = 0.5f * b4.w;
        }
#pragma unroll
        for (int m = 0; m < 4; ++m) {
            int tok = rowbase + wr + m * 16 + fr;
            float wp = wpos[tok];
#pragma unroll
            for (int n = 0; n < 4; ++n) {
                int ch = colbase + wc + n * 16 + fq * 4;
                float4 o;
                o.x = wp * (acc[m][n][0] + bb[n].x);
                o.y = wp * (acc[m][n][1] + bb[n].y);
                o.z = wp * (acc[m][n][2] + bb[n].z);
                o.w = wp * (acc[m][n][3] + bb[n].w);
                *reinterpret_cast<float4*>(&Yp[(size_t)tok * DD + ch]) = o;
            }
        }
    }
}

// ---------------- combine: out[t] = sum over {pos0,pos1} x {sk0,sk1} ----------------
__global__ __launch_bounds__(256) void combine_kernel(
    const float* __restrict__ Yb, const int* __restrict__ pos_of,
    const float* __restrict__ bias, float* __restrict__ out, int T, int maxP)
{
    int i = blockIdx.x * blockDim.x + threadIdx.x;
    int total = T * (DD / 4);
    size_t Ysz = (size_t)maxP * DD;
    if (i < total) {
        int t = i / (DD / 4);
        int c = (i % (DD / 4)) * 4;
        int p0 = pos_of[2 * t], p1 = pos_of[2 * t + 1];
        float4 v00 = *reinterpret_cast<const float4*>(&Yb[(size_t)p0 * DD + c]);
        float4 v01 = *reinterpret_cast<const float4*>(&Yb[Ysz + (size_t)p0 * DD + c]);
        float4 v10 = *reinterpret_cast<const float4*>(&Yb[(size_t)p1 * DD + c]);
        float4 v11 = *reinterpret_cast<const float4*>(&Yb[Ysz + (size_t)p1 * DD + c]);
        float4 o;
        o.x = v00.x + v01.x + v10.x + v11.x;
        o.y = v00.y + v01.y + v10.y + v11.y;
        o.z = v00.z + v01.z + v10.z + v11.z;
        o.w = v00.w + v01.w + v10.w + v11.w;
        *reinterpret_cast<float4*>(&out[(size_t)t * DD + c]) = o;
    } else if (i < total + DD / 4) {
        int c = (i - total) * 4;
        *reinterpret_cast<float4*>(&out[(size_t)T * DD + c]) =
            *reinterpret_cast<const float4*>(&bias[c]);
    }
}

extern "C" void kernel_launch(void* const* d_in, const int* in_sizes, int n_in,
                              void* d_out, int out_size, void* d_ws, size_t ws_size,
                              hipStream_t stream)
{
    const float* x    = (const float*)d_in[0];
    const float* gw   = (const float*)d_in[1];
    const float* gb   = (const float*)d_in[2];
    const float* w1   = (const float*)d_in[3];
    const float* b1   = (const float*)d_in[4];
    const float* w2   = (const float*)d_in[5];
    const float* b2   = (const float*)d_in[6];
    const float* bias = (const float*)d_in[7];
    float* out = (float*)d_out;

    int T = in_sizes[0] / DD;
    int nA = T * TOPK;
    int maxP = nA + NE * 128;

    char* ws = (char*)d_ws;
    size_t off = 0;
    auto alloc = [&](size_t bytes) -> char* {
        char* p = ws + off;
        off += (bytes + 255) & ~(size_t)255;
        return p;
    };
    unsigned short* w1b = (unsigned short*)alloc((size_t)NE * HH * DD * 2);
    unsigned short* w2b = (unsigned short*)alloc((size_t)NE * DD * HH * 2);
    unsigned short* Xe  = (unsigned short*)alloc((size_t)maxP * DD * 2);
    unsigned short* H1  = (unsigned short*)alloc((size_t)maxP * HH * 2);
    float*  Yb          = (float*)alloc((size_t)SK2 * maxP * DD * 4);
    int*    topk_idx    = (int*)alloc((size_t)nA * 4);
    float*  topk_w      = (float*)alloc((size_t)nA * 4);
    int*    pos_of      = (int*)alloc((size_t)nA * 4);
    float*  wpos        = (float*)alloc((size_t)maxP * 4);
    int*    token_map   = (int*)alloc((size_t)maxP * 4);
    int*    ctrl        = (int*)alloc(64 * 4);

    size_t nW = (size_t)NE * HH * DD;

    hipLaunchKernelGGL(convert_kernel, dim3(4096), dim3(256), 0, stream,
                       w1, w2, w1b, w2b, nW);
    hipLaunchKernelGGL(init_kernel, dim3((maxP + 255) / 256), dim3(256), 0, stream,
                       token_map, ctrl, maxP);
    hipLaunchKernelGGL(gate_kernel, dim3(512), dim3(256), 0, stream,
                       x, gw, gb, topk_idx, topk_w, ctrl, T);
    hipLaunchKernelGGL(offsets_kernel, dim3(1), dim3(64), 0, stream, ctrl);
    hipLaunchKernelGGL(scatter_kernel, dim3((nA + 255) / 256), dim3(256), 0, stream,
                       topk_idx, topk_w, ctrl, token_map, pos_of, wpos, nA);
    hipLaunchKernelGGL(gather_kernel, dim3((maxP * (DD / 4) + 255) / 256), dim3(256), 0, stream,
                       x, token_map, Xe, maxP);
    hipLaunchKernelGGL(gemm1_kernel, dim3(512), dim3(256), 0, stream,
                       Xe, w1b, b1, H1, ctrl);
    hipLaunchKernelGGL(gemm2_kernel, dim3(512), dim3(256), 0, stream,
                       H1, w2b, b2, wpos, Yb, ctrl, maxP);
    hipLaunchKernelGGL(combine_kernel, dim3((T * (DD / 4) + DD / 4 + 255) / 256, 1, 1), dim3(256), 0, stream,
                       Yb, pos_of, bias, out, T, maxP);
}